// Round 6
// baseline (884.668 us; speedup 1.0000x reference)
//
#include <hip/hip_runtime.h>

// ---------------- problem constants ----------------
#define B_ 2
#define S_ 2048
#define HID_ 2048
#define H_ 8
#define D_ 256
#define NQKV 2560   // H*D + D + D
// THETA = 10000, ln(10000) = 9.210340371976184

typedef unsigned short u16;
typedef __attribute__((ext_vector_type(8))) short bf16x8;   // 8 bf16 in 4 VGPRs
typedef __attribute__((ext_vector_type(4))) float f32x4;

__device__ __forceinline__ u16 f2b(float x) {
    unsigned u = __float_as_uint(x);
    unsigned rb = (u >> 16) & 1u;
    u += 0x7fffu + rb;               // round-to-nearest-even
    return (u16)(u >> 16);
}

__device__ __forceinline__ void load_lds16(const u16* g, u16* l) {
    // async 16B/lane global->LDS; HW writes lane i at l + i*16B (wave-uniform base)
    __builtin_amdgcn_global_load_lds(
        (const __attribute__((address_space(1))) void*)g,
        (__attribute__((address_space(3))) void*)l, 16, 0, 0);
}

// ---------------- fp32 -> bf16 convert ----------------
__global__ __launch_bounds__(256) void cvt_bf16(const float* __restrict__ in,
                                                u16* __restrict__ out, int n) {
    int i = (blockIdx.x * 256 + threadIdx.x) * 4;
    if (i >= n) return;
    float4 f = *(const float4*)(in + i);
    union { u16 u[4]; uint2 v; } pk;
    pk.u[0] = f2b(f.x); pk.u[1] = f2b(f.y); pk.u[2] = f2b(f.z); pk.u[3] = f2b(f.w);
    *(uint2*)(out + i) = pk.v;
}

__global__ __launch_bounds__(256) void concat_bias(const float* __restrict__ bq,
                                                   const float* __restrict__ bk,
                                                   const float* __restrict__ bv,
                                                   float* __restrict__ dst) {
    int i = blockIdx.x * 256 + threadIdx.x;
    if (i >= NQKV) return;
    float v;
    if (i < H_ * D_) v = bq[i];
    else if (i < H_ * D_ + D_) v = bk[i - H_ * D_];
    else v = bv[i - H_ * D_ - D_];
    dst[i] = v;
}

// ---------------- RoPE: fp32 strided src -> bf16 (B,S,nH,D) ----------------
__global__ __launch_bounds__(256) void rope_kernel(const float* __restrict__ x,
                                                   int rowStride, int colOff,
                                                   const int* __restrict__ pos_ids,
                                                   u16* __restrict__ out, int nHeads) {
    int idx = blockIdx.x * 256 + threadIdx.x;   // over B*S*nHeads*128
    int d   = idx & 127;
    int tmp = idx >> 7;
    int h   = tmp % nHeads;
    int n   = tmp / nHeads;                     // n = b*S + s
    int pos = pos_ids[n];
    float ang = (float)pos * expf(-(float)d * (9.210340371976184f / 128.0f));
    float s, c;
    sincosf(ang, &s, &c);
    size_t src = (size_t)n * rowStride + colOff + (size_t)h * D_;
    float x1 = x[src + d], x2 = x[src + d + 128];
    size_t dst = ((size_t)n * nHeads + h) * D_;
    out[dst + d]       = f2b(c * x1 - s * x2);
    out[dst + d + 128] = f2b(s * x1 + c * x2);
}

// ---------------- V transpose: fp32 strided (B,S,D) -> bf16 (B,D,S) ----------------
__global__ __launch_bounds__(256) void transpose_v(const float* __restrict__ v,
                                                   int rowStride, int colOff,
                                                   u16* __restrict__ vT) {
    __shared__ float t[32][33];
    int b = blockIdx.z;
    int s0 = blockIdx.x * 32, d0 = blockIdx.y * 32;
    int tx = threadIdx.x, ty = threadIdx.y;     // 32 x 8
#pragma unroll
    for (int i = 0; i < 4; ++i)
        t[ty + i * 8][tx] = v[((size_t)b * S_ + s0 + ty + i * 8) * rowStride + colOff + d0 + tx];
    __syncthreads();
#pragma unroll
    for (int i = 0; i < 4; ++i)
        vT[(size_t)b * D_ * S_ + (size_t)(d0 + ty + i * 8) * S_ + s0 + tx] = f2b(t[tx][ty + i * 8]);
}

// ======= fused QK^T + scale + mask + softmax (+bf16 copy), v5: K in registers =======
// Block: 256 threads (4 waves), one (b,h), 16 query rows, all 2048 key cols in regs.
// Wave w owns score cols ct*64 + w*16 + l15 -> acc[32] (128 regs).
// NO LDS for K/Q (zero cross-wave sharing -> LDS was pure overhead): each wave loads
// its own K fragments global->VGPR, 2-deep register double-buffer (bvA/bvB, parity
// static under full unroll). Loads(t+1) issue BEFORE the 8-MFMA chain of tile t, so
// the compiler's counted vmcnt hides ~L2 latency under ~300 cycles of compute.
// No barriers in the K loop; 2 blocks/CU decorrelate freely.
__global__ __launch_bounds__(256, 2) void score_softmax(
    const u16* __restrict__ q_b, const u16* __restrict__ k_b,
    const float* __restrict__ mask, float* __restrict__ attn,
    u16* __restrict__ attn_b) {
    __shared__ float redm[4][16], reds[4][16];

    const int z = blockIdx.z;
    const int bb = z >> 3, hh = z & 7;              // H_ == 8
    const int n0 = blockIdx.x * 16;
    const int tid = threadIdx.x;
    const int lane = tid & 63, wave = tid >> 6;     // wave == col-group
    const int l15 = lane & 15, quad = lane >> 4;

    // per-lane source rows (A: Q row n0+l15; B: K row wave*16+l15 + t*64)
    const u16* qrow = q_b + (((size_t)bb * S_ + n0 + l15) * H_ + hh) * D_ + quad * 8;
    const u16* krow = k_b + ((size_t)bb * S_ + wave * 16 + l15) * D_ + quad * 8;

    // A fragments (16 rows x 256 K), 32 VGPR, read once
    bf16x8 av[8];
#pragma unroll
    for (int kk = 0; kk < 8; ++kk)
        av[kk] = *(const bf16x8*)(qrow + kk * 32);

    f32x4 acc[32];
#pragma unroll
    for (int ct = 0; ct < 32; ++ct)
#pragma unroll
        for (int r = 0; r < 4; ++r) acc[ct][r] = 0.f;

    // register double-buffer for K fragments
    bf16x8 bvA[8], bvB[8];
#pragma unroll
    for (int kk = 0; kk < 8; ++kk)
        bvA[kk] = *(const bf16x8*)(krow + kk * 32);  // tile 0

#pragma unroll
    for (int t = 0; t < 32; ++t) {
        // issue prefetch of tile t+1 into the idle buffer (static parity)
        if (t < 31) {
            const u16* src = krow + (size_t)(t + 1) * 64 * D_;
            if (t & 1) {
#pragma unroll
                for (int kk = 0; kk < 8; ++kk) bvA[kk] = *(const bf16x8*)(src + kk * 32);
            } else {
#pragma unroll
                for (int kk = 0; kk < 8; ++kk) bvB[kk] = *(const bf16x8*)(src + kk * 32);
            }
        }
        // consume tile t (loaded in previous iteration / prologue)
        if (t & 1) {
#pragma unroll
            for (int kk = 0; kk < 8; ++kk)
                acc[t] = __builtin_amdgcn_mfma_f32_16x16x32_bf16(av[kk], bvB[kk], acc[t], 0, 0, 0);
        } else {
#pragma unroll
            for (int kk = 0; kk < 8; ++kk)
                acc[t] = __builtin_amdgcn_mfma_f32_16x16x32_bf16(av[kk], bvA[kk], acc[t], 0, 0, 0);
        }
    }

    // ---- scale + mask, row max (C layout: col = l15, row = quad*4 + r)
    const float sc = 0.0625f;                       // D^-0.5
    const float* maskb = mask + (size_t)bb * S_ + wave * 16 + l15;
    float mx[4] = {-3.4e38f, -3.4e38f, -3.4e38f, -3.4e38f};
#pragma unroll
    for (int ct = 0; ct < 32; ++ct) {
        float mkv = maskb[ct * 64];
#pragma unroll
        for (int r = 0; r < 4; ++r) {
            float xv = acc[ct][r] * sc + mkv;
            acc[ct][r] = xv;
            mx[r] = fmaxf(mx[r], xv);
        }
    }
#pragma unroll
    for (int off = 1; off < 16; off <<= 1)
#pragma unroll
        for (int r = 0; r < 4; ++r) mx[r] = fmaxf(mx[r], __shfl_xor(mx[r], off));
    if (l15 == 0) {
#pragma unroll
        for (int r = 0; r < 4; ++r) redm[wave][quad * 4 + r] = mx[r];
    }
    __syncthreads();
    const float LOG2E = 1.4426950408889634f;
    float fm[4], sm[4];
#pragma unroll
    for (int r = 0; r < 4; ++r) {
        int rw = quad * 4 + r;
        fm[r] = fmaxf(fmaxf(redm[0][rw], redm[1][rw]),
                      fmaxf(redm[2][rw], redm[3][rw]));
        sm[r] = 0.f;
    }
#pragma unroll
    for (int ct = 0; ct < 32; ++ct)
#pragma unroll
        for (int r = 0; r < 4; ++r) {
            float e = exp2f((acc[ct][r] - fm[r]) * LOG2E);
            acc[ct][r] = e;
            sm[r] += e;
        }
#pragma unroll
    for (int off = 1; off < 16; off <<= 1)
#pragma unroll
        for (int r = 0; r < 4; ++r) sm[r] += __shfl_xor(sm[r], off);
    if (l15 == 0) {
#pragma unroll
        for (int r = 0; r < 4; ++r) reds[wave][quad * 4 + r] = sm[r];
    }
    __syncthreads();

    // ---- normalize + store fp32 attn (+ bf16 copy)
    size_t obase = ((size_t)(bb * H_ + hh) * S_ + n0 + quad * 4) * S_
                 + wave * 16 + l15;
#pragma unroll
    for (int r = 0; r < 4; ++r) {
        int rw = quad * 4 + r;
        float inv = 1.f / (reds[0][rw] + reds[1][rw] + reds[2][rw] + reds[3][rw]);
        float* ao = attn + obase + (size_t)r * S_;
#pragma unroll
        for (int ct = 0; ct < 32; ++ct) {
            float p = acc[ct][r] * inv;
            ao[ct * 64] = p;
            acc[ct][r] = p;
        }
    }
    if (attn_b) {
        u16* ab = attn_b + obase;
#pragma unroll
        for (int r = 0; r < 4; ++r) {
            u16* abr = ab + (size_t)r * S_;
#pragma unroll
            for (int ct = 0; ct < 32; ++ct) abr[ct * 64] = f2b(acc[ct][r]);
        }
    }
}

// ================= async-staged NT GEMM (m97 structure + XOR swizzle) =================
// C(MxN) = A(MxK) * B(NxK)^T (+bias). A,B bf16. C fp32 or bf16.
#define TILE_M 128
#define TILE_N 128
#define TILE_K 32

template <bool C_IS_BF16>
__global__ __launch_bounds__(256, 2) void gemm_async(
    const u16* __restrict__ Ap, const u16* __restrict__ Bp, void* __restrict__ Cp,
    const float* __restrict__ bias, int lda, int ldb, int ldc, int K,
    long sAb, long sAh, long sBb, long sBh, long sCb, long sCh, int numH) {
    __shared__ __align__(16) u16 As[TILE_M * TILE_K];
    __shared__ __align__(16) u16 Bs[TILE_N * TILE_K];

    int z = blockIdx.z;
    int bb = z / numH, hh = z % numH;
    const u16* Ab = Ap + (long)bb * sAb + (long)hh * sAh;
    const u16* Bb = Bp + (long)bb * sBb + (long)hh * sBh;
    long cOff = (long)bb * sCb + (long)hh * sCh;

    const int m0 = blockIdx.y * TILE_M;
    const int n0 = blockIdx.x * TILE_N;
    const int tid = threadIdx.x;
    const int lane = tid & 63, wave = tid >> 6;
    const int l15 = lane & 15, quad = lane >> 4;
    const int waveM = wave >> 1, waveN = wave & 1;

    f32x4 acc[4][4];
#pragma unroll
    for (int mt = 0; mt < 4; ++mt)
#pragma unroll
        for (int nt = 0; nt < 4; ++nt)
#pragma unroll
            for (int r = 0; r < 4; ++r) acc[mt][nt][r] = 0.f;

    // per-thread staging geometry (fixed over k-loop)
    int rowS[2], colS[2];
    u16 *lA[2], *lB[2];
#pragma unroll
    for (int i = 0; i < 2; ++i) {
        int c = i * 256 + tid;
        rowS[i] = c >> 2;
        colS[i] = (((c & 3) ^ ((rowS[i] >> 1) & 3)) * 8);   // XOR-swizzled K-group
        lA[i] = As + (size_t)(i * 256 + wave * 64) * 8;
        lB[i] = Bs + (size_t)(i * 256 + wave * 64) * 8;
    }

    for (int k0 = 0; k0 < K; k0 += TILE_K) {
#pragma unroll
        for (int i = 0; i < 2; ++i) {
            load_lds16(Ab + (size_t)(m0 + rowS[i]) * lda + k0 + colS[i], lA[i]);
            load_lds16(Bb + (size_t)(n0 + rowS[i]) * ldb + k0 + colS[i], lB[i]);
        }
        __syncthreads();   // drains vmcnt (global_load_lds) per barrier semantics

        bf16x8 av[4], bv[4];
#pragma unroll
        for (int t = 0; t < 4; ++t) {
            int ra = waveM * 64 + t * 16 + l15;
            av[t] = *(bf16x8*)&As[ra * TILE_K + ((quad ^ ((ra >> 1) & 3)) * 8)];
            int rb = waveN * 64 + t * 16 + l15;
            bv[t] = *(bf16x8*)&Bs[rb * TILE_K + ((quad ^ ((rb >> 1) & 3)) * 8)];
        }
#pragma unroll
        for (int mt = 0; mt < 4; ++mt)
#pragma unroll
            for (int nt = 0; nt < 4; ++nt)
                acc[mt][nt] = __builtin_amdgcn_mfma_f32_16x16x32_bf16(av[mt], bv[nt],
                                                                      acc[mt][nt], 0, 0, 0);
        __syncthreads();
    }

    // epilogue: C/D layout col = lane&15, row = quad*4 + r
#pragma unroll
    for (int mt = 0; mt < 4; ++mt) {
        int row = m0 + waveM * 64 + mt * 16 + quad * 4;
#pragma unroll
        for (int nt = 0; nt < 4; ++nt) {
            int col = n0 + waveN * 64 + nt * 16 + l15;
            float bia = bias ? bias[col] : 0.f;
#pragma unroll
            for (int r = 0; r < 4; ++r) {
                float val = acc[mt][nt][r] + bia;
                if constexpr (C_IS_BF16)
                    ((u16*)Cp)[cOff + (size_t)(row + r) * ldc + col] = f2b(val);
                else
                    ((float*)Cp)[cOff + (size_t)(row + r) * ldc + col] = val;
            }
        }
    }
}

// ---------------- fallback GEMM (A fp32, staged via VGPR) — used only if ws too small ----
#define LDSK 40
__global__ __launch_bounds__(256, 2) void gemm_slow_f32a(
    const float* __restrict__ Ap, const u16* __restrict__ Bp, u16* __restrict__ Cp,
    int lda, int ldb, int ldc, int K,
    long sAb, long sAh, long sBb, long sBh, long sCb, long sCh, int numH) {
    __shared__ __align__(16) u16 As[TILE_M * LDSK];
    __shared__ __align__(16) u16 Bs[TILE_N * LDSK];
    int z = blockIdx.z;
    int bb = z / numH, hh = z % numH;
    const float* Af = Ap + (long)bb * sAb + (long)hh * sAh;
    const u16* Bb = Bp + (long)bb * sBb + (long)hh * sBh;
    long cOff = (long)bb * sCb + (long)hh * sCh;
    const int m0 = blockIdx.y * TILE_M, n0 = blockIdx.x * TILE_N;
    const int tid = threadIdx.x;
    const int lane = tid & 63, wave = tid >> 6;
    const int l15 = lane & 15, quad = lane >> 4;
    const int waveM = wave >> 1, waveN = wave & 1;
    f32x4 acc[4][4];
#pragma unroll
    for (int mt = 0; mt < 4; ++mt)
#pragma unroll
        for (int nt = 0; nt < 4; ++nt)
#pragma unroll
            for (int r = 0; r < 4; ++r) acc[mt][nt][r] = 0.f;
    for (int k0 = 0; k0 < K; k0 += TILE_K) {
#pragma unroll
        for (int i = 0; i < 2; ++i) {
            int c = tid + i * 256;
            int row = c >> 2, col = (c & 3) * 8;
            const float* src = Af + (size_t)(m0 + row) * lda + k0 + col;
            float4 f0 = *(const float4*)src;
            float4 f1 = *(const float4*)(src + 4);
            union { u16 u[8]; uint4 v; } pk;
            pk.u[0] = f2b(f0.x); pk.u[1] = f2b(f0.y); pk.u[2] = f2b(f0.z); pk.u[3] = f2b(f0.w);
            pk.u[4] = f2b(f1.x); pk.u[5] = f2b(f1.y); pk.u[6] = f2b(f1.z); pk.u[7] = f2b(f1.w);
            *(uint4*)&As[row * LDSK + col] = pk.v;
            *(uint4*)&Bs[row * LDSK + col] =
                *(const uint4*)(Bb + (size_t)(n0 + row) * ldb + k0 + col);
        }
        __syncthreads();
        bf16x8 av[4], bv[4];
#pragma unroll
        for (int t = 0; t < 4; ++t) {
            av[t] = *(bf16x8*)&As[(waveM * 64 + t * 16 + l15) * LDSK + quad * 8];
            bv[t] = *(bf16x8*)&Bs[(waveN * 64 + t * 16 + l15) * LDSK + quad * 8];
        }
#pragma unroll
        for (int mt = 0; mt < 4; ++mt)
#pragma unroll
            for (int nt = 0; nt < 4; ++nt)
                acc[mt][nt] = __builtin_amdgcn_mfma_f32_16x16x32_bf16(av[mt], bv[nt],
                                                                      acc[mt][nt], 0, 0, 0);
        __syncthreads();
    }
#pragma unroll
    for (int mt = 0; mt < 4; ++mt) {
        int row = m0 + waveM * 64 + mt * 16 + quad * 4;
#pragma unroll
        for (int nt = 0; nt < 4; ++nt) {
            int col = n0 + waveN * 64 + nt * 16 + l15;
#pragma unroll
            for (int r = 0; r < 4; ++r)
                Cp[cOff + (size_t)(row + r) * ldc + col] = f2b(acc[mt][nt][r]);
        }
    }
}

// ---------------- host launcher ----------------
extern "C" void kernel_launch(void* const* d_in, const int* in_sizes, int n_in,
                              void* d_out, int out_size, void* d_ws, size_t ws_size,
                              hipStream_t stream) {
    const float* hs   = (const float*)d_in[0];
    const float* mask = (const float*)d_in[1];
    const int*   pos  = (const int*)d_in[2];
    const float* Wq = (const float*)d_in[3];
    const float* bq = (const float*)d_in[4];
    const float* Wk = (const float*)d_in[5];
    const float* bk = (const float*)d_in[6];
    const float* Wv = (const float*)d_in[7];
    const float* bv = (const float*)d_in[8];
    const float* Wo = (const float*)d_in[9];
    const float* bo = (const float*)d_in[10];

    float* out  = (float*)d_out;                          // (B,S,HID)
    float* attn = (float*)d_out + (size_t)B_ * S_ * HID_; // (B,H,S,S)

    // workspace layout
    char* ws = (char*)d_ws;
    size_t need = 0;
    u16* hs_b    = (u16*)(ws);          need += (size_t)B_ * S_ * HID_ * 2;        // 16.8 MB (reused as ctx)
    u16* Wqkv_b  = (u16*)(ws + need);   need += (size_t)NQKV * HID_ * 2;           // 10.5 MB
    u16* Wo_b    = (u16*)(ws + need);   need += (size_t)HID_ * H_ * D_ * 2;        // 8.4 MB
    float* qkv_f = (float*)(ws + need); need += (size_t)B_ * S_ * NQKV * 4;        // 41.9 MB
    u16* q_b     = (u16*)(ws + need);   need += (size_t)B_ * S_ * H_ * D_ * 2;     // 16.8 MB
    u16* k_b     = (u16*)(ws + need);   need += (size_t)B_ * S_ * D_ * 2;          // 2.1 MB
    u16* vT_b    = (u16*)(ws + need);   need += (size_t)B_ * D_ * S_ * 2;          // 2.1 MB
    float* bqkv  = (float*)(ws + need); need += (size_t)NQKV * 4 + 4096;           // pad-align
    need &= ~(size_t)255;
    u16* attn_b  = (u16*)(ws + need);
    size_t need_big = need + (size_t)B_ * H_ * S_ * S_ * 2;                        // +134 MB
    bool big = ws_size >= need_big;
    u16* ctx_b = hs_b;                  // hs_b dead after QKV projection

    // 1) convert to bf16 (weights fused into one QKV buffer)
    cvt_bf16<<<dim3((B_ * S_ * HID_) / 1024), 256, 0, stream>>>(hs, hs_b, B_ * S_ * HID_);
    cvt_bf16<<<dim3((H_ * D_ * HID_) / 1024), 256, 0, stream>>>(Wq, Wqkv_b, H_ * D_ * HID_);
    cvt_bf16<<<dim3((D_ * HID_) / 1024), 256, 0, stream>>>(Wk, Wqkv_b + (size_t)H_ * D_ * HID_, D_ * HID_);
    cvt_bf16<<<dim3((D_ * HID_) / 1024), 256, 0, stream>>>(Wv, Wqkv_b + (size_t)(H_ * D_ + D_) * HID_, D_ * HID_);
    cvt_bf16<<<dim3((HID_ * H_ * D_) / 1024), 256, 0, stream>>>(Wo, Wo_b, HID_ * H_ * D_);
    concat_bias<<<dim3((NQKV + 255) / 256), 256, 0, stream>>>(bq, bk, bv, bqkv);

    // 2) fused QKV projection: (B*S, NQKV) = hs_b @ Wqkv^T + bqkv
    gemm_async<false><<<dim3(NQKV / TILE_N, (B_ * S_) / TILE_M, 1), 256, 0, stream>>>(
        hs_b, Wqkv_b, qkv_f, bqkv, HID_, HID_, NQKV, HID_,
        0, 0, 0, 0, 0, 0, 1);

    // 3) RoPE q,k ; transpose v
    rope_kernel<<<dim3((B_ * S_ * H_ * 128) / 256), 256, 0, stream>>>(
        qkv_f, NQKV, 0, pos, q_b, H_);
    rope_kernel<<<dim3((B_ * S_ * 1 * 128) / 256), 256, 0, stream>>>(
        qkv_f, NQKV, H_ * D_, pos, k_b, 1);
    transpose_v<<<dim3(S_ / 32, D_ / 32, B_), dim3(32, 8), 0, stream>>>(
        qkv_f, NQKV, H_ * D_ + D_, vT_b);

    // 4) fused scores + scale + mask + softmax -> fp32 attn (+ bf16 copy)
    score_softmax<<<dim3(S_ / 16, 1, B_ * H_), 256, 0, stream>>>(
        q_b, k_b, mask, attn, big ? attn_b : nullptr);

    // 5) ctx = attn @ V
    if (big) {
        gemm_async<true><<<dim3(D_ / TILE_N, S_ / TILE_M, B_ * H_), 256, 0, stream>>>(
            attn_b, vT_b, ctx_b, nullptr, S_, S_, H_ * D_, S_,
            (long)H_ * S_ * S_, (long)S_ * S_,
            (long)D_ * S_, 0,
            (long)S_ * H_ * D_, D_,
            H_);
    } else {
        gemm_slow_f32a<<<dim3(D_ / TILE_N, S_ / TILE_M, B_ * H_), 256, 0, stream>>>(
            attn, vT_b, ctx_b, S_, S_, H_ * D_, S_,
            (long)H_ * S_ * S_, (long)S_ * S_,
            (long)D_ * S_, 0,
            (long)S_ * H_ * D_, D_,
            H_);
    }

    // 6) out = ctx @ Wo^T + bo
    gemm_async<false><<<dim3(HID_ / TILE_N, (B_ * S_) / TILE_M, 1), 256, 0, stream>>>(
        ctx_b, Wo_b, out, bo, H_ * D_, H_ * D_, HID_, H_ * D_,
        0, 0, 0, 0, 0, 0, 1);
}

// Round 8
// 702.755 us; speedup vs baseline: 1.2589x; 1.2589x over previous
//
#include <hip/hip_runtime.h>

// ---------------- problem constants ----------------
#define B_ 2
#define S_ 2048
#define HID_ 2048
#define H_ 8
#define D_ 256
#define NQKV 2560   // H*D + D + D

typedef unsigned short u16;
typedef __attribute__((ext_vector_type(8))) short bf16x8;   // 8 bf16 in 4 VGPRs
typedef __attribute__((ext_vector_type(4))) float f32x4;

__device__ __forceinline__ u16 f2b(float x) {
    unsigned u = __float_as_uint(x);
    unsigned rb = (u >> 16) & 1u;
    u += 0x7fffu + rb;               // round-to-nearest-even
    return (u16)(u >> 16);
}

__device__ __forceinline__ void load_lds16(const u16* g, u16* l) {
    // async 16B/lane global->LDS; HW writes lane i at l + i*16B (wave-uniform base)
    __builtin_amdgcn_global_load_lds(
        (const __attribute__((address_space(1))) void*)g,
        (__attribute__((address_space(3))) void*)l, 16, 0, 0);
}

// ---------------- fp32 -> bf16 convert ----------------
__global__ __launch_bounds__(256) void cvt_bf16(const float* __restrict__ in,
                                                u16* __restrict__ out, int n) {
    int i = (blockIdx.x * 256 + threadIdx.x) * 4;
    if (i >= n) return;
    float4 f = *(const float4*)(in + i);
    union { u16 u[4]; uint2 v; } pk;
    pk.u[0] = f2b(f.x); pk.u[1] = f2b(f.y); pk.u[2] = f2b(f.z); pk.u[3] = f2b(f.w);
    *(uint2*)(out + i) = pk.v;
}

__global__ __launch_bounds__(256) void concat_bias(const float* __restrict__ bq,
                                                   const float* __restrict__ bk,
                                                   const float* __restrict__ bv,
                                                   float* __restrict__ dst) {
    int i = blockIdx.x * 256 + threadIdx.x;
    if (i >= NQKV) return;
    float v;
    if (i < H_ * D_) v = bq[i];
    else if (i < H_ * D_ + D_) v = bk[i - H_ * D_];
    else v = bv[i - H_ * D_ - D_];
    dst[i] = v;
}

// ---------------- RoPE: fp32 strided src -> bf16 (B,S,nH,D) ----------------
__global__ __launch_bounds__(256) void rope_kernel(const float* __restrict__ x,
                                                   int rowStride, int colOff,
                                                   const int* __restrict__ pos_ids,
                                                   u16* __restrict__ out, int nHeads) {
    int idx = blockIdx.x * 256 + threadIdx.x;   // over B*S*nHeads*128
    int d   = idx & 127;
    int tmp = idx >> 7;
    int h   = tmp % nHeads;
    int n   = tmp / nHeads;                     // n = b*S + s
    int pos = pos_ids[n];
    float ang = (float)pos * expf(-(float)d * (9.210340371976184f / 128.0f));
    float s, c;
    sincosf(ang, &s, &c);
    size_t src = (size_t)n * rowStride + colOff + (size_t)h * D_;
    float x1 = x[src + d], x2 = x[src + d + 128];
    size_t dst = ((size_t)n * nHeads + h) * D_;
    out[dst + d]       = f2b(c * x1 - s * x2);
    out[dst + d + 128] = f2b(s * x1 + c * x2);
}

// ---------------- V transpose: fp32 strided (B,S,D) -> bf16 (B,D,S) ----------------
__global__ __launch_bounds__(256) void transpose_v(const float* __restrict__ v,
                                                   int rowStride, int colOff,
                                                   u16* __restrict__ vT) {
    __shared__ float t[32][33];
    int b = blockIdx.z;
    int s0 = blockIdx.x * 32, d0 = blockIdx.y * 32;
    int tx = threadIdx.x, ty = threadIdx.y;     // 32 x 8
#pragma unroll
    for (int i = 0; i < 4; ++i)
        t[ty + i * 8][tx] = v[((size_t)b * S_ + s0 + ty + i * 8) * rowStride + colOff + d0 + tx];
    __syncthreads();
#pragma unroll
    for (int i = 0; i < 4; ++i)
        vT[(size_t)b * D_ * S_ + (size_t)(d0 + ty + i * 8) * S_ + s0 + tx] = f2b(t[tx][ty + i * 8]);
}

// ==== fused QK^T + scale + mask + softmax (+bf16 copy), v7: race-fixed counted vmcnt ====
// Same as v6 (per-wave K rows, per-wave dbuf LDS, no barriers in K loop) with the race
// closed: the hazard was iteration t's STAGE_K(t+1 -> buf[(t+1)&1]) overwriting the
// buffer read by iteration t-1's ds_reads -- the compiler interleaved the DMA issues
// above the register-only MFMAs + their lgkm waits (rule #18). Fix: sched_barrier(0)
// at iteration top + explicit lgkmcnt(0) BEFORE the STAGE (prior ds_reads complete,
// ~free since their MFMAs already forced completion), then vmcnt(8) + sched_barrier(0).
__global__ __launch_bounds__(256, 2) void score_softmax(
    const u16* __restrict__ q_b, const u16* __restrict__ k_b,
    const float* __restrict__ mask, float* __restrict__ attn,
    u16* __restrict__ attn_b) {
    __shared__ __align__(16) u16 qs[16 * 256];      // 8 KB (shared across waves)
    __shared__ __align__(16) u16 ks[2][64 * 256];   // 2 x 32 KB (per-wave 16-row slices)
    __shared__ float redm[4][16], reds[4][16];

    const int z = blockIdx.z;
    const int bb = z >> 3, hh = z & 7;              // H_ == 8
    const int n0 = blockIdx.x * 16;
    const int tid = threadIdx.x;
    const int lane = tid & 63, wave = tid >> 6;     // wave == col-group
    const int l15 = lane & 15, quad = lane >> 4;
    const int hi = lane >> 5, l31 = lane & 31;      // staging lane split

    const u16* qsrc  = q_b + (((size_t)bb * S_ + n0) * H_ + hh) * D_;
    const u16* kbase = k_b + (size_t)bb * S_ * D_;

    // ---- stage Q tile (cooperative, 16 x 256 = 8 KB), swizzled source
    const int tr5 = tid >> 5;
    const int gsw = ((tid & 31) ^ tr5) * 8;         // involution slot
#pragma unroll
    for (int i = 0; i < 2; ++i)
        load_lds16(qsrc + (size_t)(i * 8 + tr5) * (H_ * D_) + gsw,
                   qs + (size_t)(i * 256 + wave * 64) * 8);

    // ---- per-wave K staging geometry: issue j stages tile rows w*16+2j..w*16+2j+1
    // lane l -> row_local 2j+hi, slot l31; src col-group = l31 ^ ((2j+hi)&7)
    size_t ksrc[8];                                  // static-indexed under unroll
#pragma unroll
    for (int j = 0; j < 8; ++j)
        ksrc[j] = (size_t)(wave * 16 + 2 * j + hi) * D_ + ((l31 ^ ((2 * j + hi) & 7)) * 8);

#define STAGE_K(tile, buf)                                                       \
    _Pragma("unroll")                                                            \
    for (int j = 0; j < 8; ++j)                                                  \
        load_lds16(kbase + (size_t)(tile) * 64 * D_ + ksrc[j],                   \
                   ks[buf] + (size_t)(wave * 16 + 2 * j) * 256);

    STAGE_K(0, 0);

    f32x4 acc[32];
#pragma unroll
    for (int ct = 0; ct < 32; ++ct)
#pragma unroll
        for (int r = 0; r < 4; ++r) acc[ct][r] = 0.f;

    __syncthreads();                                // drain Q + K0; ONLY barrier pre-softmax

    // ---- A fragments (16 rows x 256 K), 32 VGPR, for the whole loop
    bf16x8 av[8];
#pragma unroll
    for (int kk = 0; kk < 8; ++kk)
        av[kk] = *(const bf16x8*)&qs[l15 * 256 + (((kk * 4 + quad) ^ (l15 & 7)) * 8)];

    const int rb = wave * 16 + l15;                 // tile-local K row (fixed)
    const int rbo = rb * 256;

    // ---- K loop: 32 tiles, per-wave dbuf, counted vmcnt, no barriers
#pragma unroll
    for (int t = 0; t < 32; ++t) {
        __builtin_amdgcn_sched_barrier(0);          // pin iteration structure
        if (t < 31) {
            // prior iteration's ds_reads of buf[(t+1)&1] MUST be complete before
            // the DMA overwrite issues (in-order wave execution does the rest)
            asm volatile("s_waitcnt lgkmcnt(0)" ::: "memory");
            STAGE_K(t + 1, (t + 1) & 1);
            asm volatile("s_waitcnt vmcnt(8)" ::: "memory");   // tile t's 8 DMAs done
        } else {
            asm volatile("s_waitcnt vmcnt(0)" ::: "memory");
        }
        __builtin_amdgcn_sched_barrier(0);          // no ds_read hoisting (rule #18)
        const u16* kst = ks[t & 1];
        bf16x8 bv[8];
#pragma unroll
        for (int kk = 0; kk < 8; ++kk)
            bv[kk] = *(const bf16x8*)&kst[rbo + (((kk * 4 + quad) ^ (rb & 7)) * 8)];
#pragma unroll
        for (int kk = 0; kk < 8; ++kk)
            acc[t] = __builtin_amdgcn_mfma_f32_16x16x32_bf16(av[kk], bv[kk], acc[t], 0, 0, 0);
    }
#undef STAGE_K

    // ---- scale + mask, row max (C layout: col = l15, row = quad*4 + r)
    const float sc = 0.0625f;                       // D^-0.5
    const float* maskb = mask + (size_t)bb * S_ + wave * 16 + l15;
    float mx[4] = {-3.4e38f, -3.4e38f, -3.4e38f, -3.4e38f};
#pragma unroll
    for (int ct = 0; ct < 32; ++ct) {
        float mkv = maskb[ct * 64];
#pragma unroll
        for (int r = 0; r < 4; ++r) {
            float xv = acc[ct][r] * sc + mkv;
            acc[ct][r] = xv;
            mx[r] = fmaxf(mx[r], xv);
        }
    }
#pragma unroll
    for (int off = 1; off < 16; off <<= 1)
#pragma unroll
        for (int r = 0; r < 4; ++r) mx[r] = fmaxf(mx[r], __shfl_xor(mx[r], off));
    if (l15 == 0) {
#pragma unroll
        for (int r = 0; r < 4; ++r) redm[wave][quad * 4 + r] = mx[r];
    }
    __syncthreads();
    const float LOG2E = 1.4426950408889634f;
    float fm[4], sm[4];
#pragma unroll
    for (int r = 0; r < 4; ++r) {
        int rw = quad * 4 + r;
        fm[r] = fmaxf(fmaxf(redm[0][rw], redm[1][rw]),
                      fmaxf(redm[2][rw], redm[3][rw]));
        sm[r] = 0.f;
    }
#pragma unroll
    for (int ct = 0; ct < 32; ++ct)
#pragma unroll
        for (int r = 0; r < 4; ++r) {
            float e = exp2f((acc[ct][r] - fm[r]) * LOG2E);
            acc[ct][r] = e;
            sm[r] += e;
        }
#pragma unroll
    for (int off = 1; off < 16; off <<= 1)
#pragma unroll
        for (int r = 0; r < 4; ++r) sm[r] += __shfl_xor(sm[r], off);
    if (l15 == 0) {
#pragma unroll
        for (int r = 0; r < 4; ++r) reds[wave][quad * 4 + r] = sm[r];
    }
    __syncthreads();

    // ---- normalize + store fp32 attn (+ bf16 copy)
    size_t obase = ((size_t)(bb * H_ + hh) * S_ + n0 + quad * 4) * S_
                 + wave * 16 + l15;
#pragma unroll
    for (int r = 0; r < 4; ++r) {
        int rw = quad * 4 + r;
        float inv = 1.f / (reds[0][rw] + reds[1][rw] + reds[2][rw] + reds[3][rw]);
        float* ao = attn + obase + (size_t)r * S_;
#pragma unroll
        for (int ct = 0; ct < 32; ++ct) {
            float p = acc[ct][r] * inv;
            ao[ct * 64] = p;
            acc[ct][r] = p;
        }
    }
    if (attn_b) {
        u16* ab = attn_b + obase;
#pragma unroll
        for (int r = 0; r < 4; ++r) {
            u16* abr = ab + (size_t)r * S_;
#pragma unroll
            for (int ct = 0; ct < 32; ++ct) abr[ct * 64] = f2b(acc[ct][r]);
        }
    }
}

// ================= async-staged NT GEMM (m97 structure + XOR swizzle) =================
// C(MxN) = A(MxK) * B(NxK)^T (+bias). A,B bf16. C fp32 or bf16.
#define TILE_M 128
#define TILE_N 128
#define TILE_K 32

template <bool C_IS_BF16>
__global__ __launch_bounds__(256, 2) void gemm_async(
    const u16* __restrict__ Ap, const u16* __restrict__ Bp, void* __restrict__ Cp,
    const float* __restrict__ bias, int lda, int ldb, int ldc, int K,
    long sAb, long sAh, long sBb, long sBh, long sCb, long sCh, int numH) {
    __shared__ __align__(16) u16 As[TILE_M * TILE_K];
    __shared__ __align__(16) u16 Bs[TILE_N * TILE_K];

    int z = blockIdx.z;
    int bb = z / numH, hh = z % numH;
    const u16* Ab = Ap + (long)bb * sAb + (long)hh * sAh;
    const u16* Bb = Bp + (long)bb * sBb + (long)hh * sBh;
    long cOff = (long)bb * sCb + (long)hh * sCh;

    const int m0 = blockIdx.y * TILE_M;
    const int n0 = blockIdx.x * TILE_N;
    const int tid = threadIdx.x;
    const int lane = tid & 63, wave = tid >> 6;
    const int l15 = lane & 15, quad = lane >> 4;
    const int waveM = wave >> 1, waveN = wave & 1;

    f32x4 acc[4][4];
#pragma unroll
    for (int mt = 0; mt < 4; ++mt)
#pragma unroll
        for (int nt = 0; nt < 4; ++nt)
#pragma unroll
            for (int r = 0; r < 4; ++r) acc[mt][nt][r] = 0.f;

    // per-thread staging geometry (fixed over k-loop)
    int rowS[2], colS[2];
    u16 *lA[2], *lB[2];
#pragma unroll
    for (int i = 0; i < 2; ++i) {
        int c = i * 256 + tid;
        rowS[i] = c >> 2;
        colS[i] = (((c & 3) ^ ((rowS[i] >> 1) & 3)) * 8);   // XOR-swizzled K-group
        lA[i] = As + (size_t)(i * 256 + wave * 64) * 8;
        lB[i] = Bs + (size_t)(i * 256 + wave * 64) * 8;
    }

    for (int k0 = 0; k0 < K; k0 += TILE_K) {
#pragma unroll
        for (int i = 0; i < 2; ++i) {
            load_lds16(Ab + (size_t)(m0 + rowS[i]) * lda + k0 + colS[i], lA[i]);
            load_lds16(Bb + (size_t)(n0 + rowS[i]) * ldb + k0 + colS[i], lB[i]);
        }
        __syncthreads();   // drains vmcnt (global_load_lds) per barrier semantics

        bf16x8 av[4], bv[4];
#pragma unroll
        for (int t = 0; t < 4; ++t) {
            int ra = waveM * 64 + t * 16 + l15;
            av[t] = *(bf16x8*)&As[ra * TILE_K + ((quad ^ ((ra >> 1) & 3)) * 8)];
            int rb = waveN * 64 + t * 16 + l15;
            bv[t] = *(bf16x8*)&Bs[rb * TILE_K + ((quad ^ ((rb >> 1) & 3)) * 8)];
        }
#pragma unroll
        for (int mt = 0; mt < 4; ++mt)
#pragma unroll
            for (int nt = 0; nt < 4; ++nt)
                acc[mt][nt] = __builtin_amdgcn_mfma_f32_16x16x32_bf16(av[mt], bv[nt],
                                                                      acc[mt][nt], 0, 0, 0);
        __syncthreads();
    }

    // epilogue: C/D layout col = lane&15, row = quad*4 + r
#pragma unroll
    for (int mt = 0; mt < 4; ++mt) {
        int row = m0 + waveM * 64 + mt * 16 + quad * 4;
#pragma unroll
        for (int nt = 0; nt < 4; ++nt) {
            int col = n0 + waveN * 64 + nt * 16 + l15;
            float bia = bias ? bias[col] : 0.f;
#pragma unroll
            for (int r = 0; r < 4; ++r) {
                float val = acc[mt][nt][r] + bia;
                if constexpr (C_IS_BF16)
                    ((u16*)Cp)[cOff + (size_t)(row + r) * ldc + col] = f2b(val);
                else
                    ((float*)Cp)[cOff + (size_t)(row + r) * ldc + col] = val;
            }
        }
    }
}

// ---------------- fallback GEMM (A fp32, staged via VGPR) — used only if ws too small ----
#define LDSK 40
__global__ __launch_bounds__(256, 2) void gemm_slow_f32a(
    const float* __restrict__ Ap, const u16* __restrict__ Bp, u16* __restrict__ Cp,
    int lda, int ldb, int ldc, int K,
    long sAb, long sAh, long sBb, long sBh, long sCb, long sCh, int numH) {
    __shared__ __align__(16) u16 As[TILE_M * LDSK];
    __shared__ __align__(16) u16 Bs[TILE_N * LDSK];
    int z = blockIdx.z;
    int bb = z / numH, hh = z % numH;
    const float* Af = Ap + (long)bb * sAb + (long)hh * sAh;
    const u16* Bb = Bp + (long)bb * sBb + (long)hh * sBh;
    long cOff = (long)bb * sCb + (long)hh * sCh;
    const int m0 = blockIdx.y * TILE_M, n0 = blockIdx.x * TILE_N;
    const int tid = threadIdx.x;
    const int lane = tid & 63, wave = tid >> 6;
    const int l15 = lane & 15, quad = lane >> 4;
    const int waveM = wave >> 1, waveN = wave & 1;
    f32x4 acc[4][4];
#pragma unroll
    for (int mt = 0; mt < 4; ++mt)
#pragma unroll
        for (int nt = 0; nt < 4; ++nt)
#pragma unroll
            for (int r = 0; r < 4; ++r) acc[mt][nt][r] = 0.f;
    for (int k0 = 0; k0 < K; k0 += TILE_K) {
#pragma unroll
        for (int i = 0; i < 2; ++i) {
            int c = tid + i * 256;
            int row = c >> 2, col = (c & 3) * 8;
            const float* src = Af + (size_t)(m0 + row) * lda + k0 + col;
            float4 f0 = *(const float4*)src;
            float4 f1 = *(const float4*)(src + 4);
            union { u16 u[8]; uint4 v; } pk;
            pk.u[0] = f2b(f0.x); pk.u[1] = f2b(f0.y); pk.u[2] = f2b(f0.z); pk.u[3] = f2b(f0.w);
            pk.u[4] = f2b(f1.x); pk.u[5] = f2b(f1.y); pk.u[6] = f2b(f1.z); pk.u[7] = f2b(f1.w);
            *(uint4*)&As[row * LDSK + col] = pk.v;
            *(uint4*)&Bs[row * LDSK + col] =
                *(const uint4*)(Bb + (size_t)(n0 + row) * ldb + k0 + col);
        }
        __syncthreads();
        bf16x8 av[4], bv[4];
#pragma unroll
        for (int t = 0; t < 4; ++t) {
            av[t] = *(bf16x8*)&As[(waveM * 64 + t * 16 + l15) * LDSK + quad * 8];
            bv[t] = *(bf16x8*)&Bs[(waveN * 64 + t * 16 + l15) * LDSK + quad * 8];
        }
#pragma unroll
        for (int mt = 0; mt < 4; ++mt)
#pragma unroll
            for (int nt = 0; nt < 4; ++nt)
                acc[mt][nt] = __builtin_amdgcn_mfma_f32_16x16x32_bf16(av[mt], bv[nt],
                                                                      acc[mt][nt], 0, 0, 0);
        __syncthreads();
    }
#pragma unroll
    for (int mt = 0; mt < 4; ++mt) {
        int row = m0 + waveM * 64 + mt * 16 + quad * 4;
#pragma unroll
        for (int nt = 0; nt < 4; ++nt) {
            int col = n0 + waveN * 64 + nt * 16 + l15;
#pragma unroll
            for (int r = 0; r < 4; ++r)
                Cp[cOff + (size_t)(row + r) * ldc + col] = f2b(acc[mt][nt][r]);
        }
    }
}

// ---------------- host launcher ----------------
extern "C" void kernel_launch(void* const* d_in, const int* in_sizes, int n_in,
                              void* d_out, int out_size, void* d_ws, size_t ws_size,
                              hipStream_t stream) {
    const float* hs   = (const float*)d_in[0];
    const float* mask = (const float*)d_in[1];
    const int*   pos  = (const int*)d_in[2];
    const float* Wq = (const float*)d_in[3];
    const float* bq = (const float*)d_in[4];
    const float* Wk = (const float*)d_in[5];
    const float* bk = (const float*)d_in[6];
    const float* Wv = (const float*)d_in[7];
    const float* bv = (const float*)d_in[8];
    const float* Wo = (const float*)d_in[9];
    const float* bo = (const float*)d_in[10];

    float* out  = (float*)d_out;                          // (B,S,HID)
    float* attn = (float*)d_out + (size_t)B_ * S_ * HID_; // (B,H,S,S)

    // workspace layout
    char* ws = (char*)d_ws;
    size_t need = 0;
    u16* hs_b    = (u16*)(ws);          need += (size_t)B_ * S_ * HID_ * 2;        // 16.8 MB (reused as ctx)
    u16* Wqkv_b  = (u16*)(ws + need);   need += (size_t)NQKV * HID_ * 2;           // 10.5 MB
    u16* Wo_b    = (u16*)(ws + need);   need += (size_t)HID_ * H_ * D_ * 2;        // 8.4 MB
    float* qkv_f = (float*)(ws + need); need += (size_t)B_ * S_ * NQKV * 4;        // 41.9 MB
    u16* q_b     = (u16*)(ws + need);   need += (size_t)B_ * S_ * H_ * D_ * 2;     // 16.8 MB
    u16* k_b     = (u16*)(ws + need);   need += (size_t)B_ * S_ * D_ * 2;          // 2.1 MB
    u16* vT_b    = (u16*)(ws + need);   need += (size_t)B_ * D_ * S_ * 2;          // 2.1 MB
    float* bqkv  = (float*)(ws + need); need += (size_t)NQKV * 4 + 4096;           // pad-align
    need &= ~(size_t)255;
    u16* attn_b  = (u16*)(ws + need);
    size_t need_big = need + (size_t)B_ * H_ * S_ * S_ * 2;                        // +134 MB
    bool big = ws_size >= need_big;
    u16* ctx_b = hs_b;                  // hs_b dead after QKV projection

    // 1) convert to bf16 (weights fused into one QKV buffer)
    cvt_bf16<<<dim3((B_ * S_ * HID_) / 1024), 256, 0, stream>>>(hs, hs_b, B_ * S_ * HID_);
    cvt_bf16<<<dim3((H_ * D_ * HID_) / 1024), 256, 0, stream>>>(Wq, Wqkv_b, H_ * D_ * HID_);
    cvt_bf16<<<dim3((D_ * HID_) / 1024), 256, 0, stream>>>(Wk, Wqkv_b + (size_t)H_ * D_ * HID_, D_ * HID_);
    cvt_bf16<<<dim3((D_ * HID_) / 1024), 256, 0, stream>>>(Wv, Wqkv_b + (size_t)(H_ * D_ + D_) * HID_, D_ * HID_);
    cvt_bf16<<<dim3((HID_ * H_ * D_) / 1024), 256, 0, stream>>>(Wo, Wo_b, HID_ * H_ * D_);
    concat_bias<<<dim3((NQKV + 255) / 256), 256, 0, stream>>>(bq, bk, bv, bqkv);

    // 2) fused QKV projection: (B*S, NQKV) = hs_b @ Wqkv^T + bqkv
    gemm_async<false><<<dim3(NQKV / TILE_N, (B_ * S_) / TILE_M, 1), 256, 0, stream>>>(
        hs_b, Wqkv_b, qkv_f, bqkv, HID_, HID_, NQKV, HID_,
        0, 0, 0, 0, 0, 0, 1);

    // 3) RoPE q,k ; transpose v
    rope_kernel<<<dim3((B_ * S_ * H_ * 128) / 256), 256, 0, stream>>>(
        qkv_f, NQKV, 0, pos, q_b, H_);
    rope_kernel<<<dim3((B_ * S_ * 1 * 128) / 256), 256, 0, stream>>>(
        qkv_f, NQKV, H_ * D_, pos, k_b, 1);
    transpose_v<<<dim3(S_ / 32, D_ / 32, B_), dim3(32, 8), 0, stream>>>(
        qkv_f, NQKV, H_ * D_ + D_, vT_b);

    // 4) fused scores + scale + mask + softmax -> fp32 attn (+ bf16 copy)
    score_softmax<<<dim3(S_ / 16, 1, B_ * H_), 256, 0, stream>>>(
        q_b, k_b, mask, attn, big ? attn_b : nullptr);

    // 5) ctx = attn @ V
    if (big) {
        gemm_async<true><<<dim3(D_ / TILE_N, S_ / TILE_M, B_ * H_), 256, 0, stream>>>(
            attn_b, vT_b, ctx_b, nullptr, S_, S_, H_ * D_, S_,
            (long)H_ * S_ * S_, (long)S_ * S_,
            (long)D_ * S_, 0,
            (long)S_ * H_ * D_, D_,
            H_);
    } else {
        gemm_slow_f32a<<<dim3(D_ / TILE_N, S_ / TILE_M, B_ * H_), 256, 0, stream>>>(
            attn, vT_b, ctx_b, S_, S_, H_ * D_, S_,
            (long)H_ * S_ * S_, (long)S_ * S_,
            (long)D_ * S_, 0,
            (long)S_ * H_ * D_, D_,
            H_);
    }

    // 6) out = ctx @ Wo^T + bo
    gemm_async<false><<<dim3(HID_ / TILE_N, (B_ * S_) / TILE_M, 1), 256, 0, stream>>>(
        ctx_b, Wo_b, out, bo, H_ * D_, H_ * D_, HID_, H_ * D_,
        0, 0, 0, 0, 0, 0, 1);
}